// Round 1
// baseline (443.092 us; speedup 1.0000x reference)
//
#include <hip/hip_runtime.h>
#include <hip/hip_bf16.h>
#include <stdint.h>

// LocalAttention: B=16, N=1024 (32x32 grid), C=1024, H=16, D=64.
// Pipeline: cvt(x,w_qkv,w_proj)->bf16 ; GEMM1 qkv = x@w_qkv^T (bf16 MFMA) ;
// local 3x3 window attention (wave per token) ; GEMM2 out = attn@w_proj^T + b.
// Workspace requirement: ~176.2 MB (x_bf 33.5 + wq 6.3 + wp 2.1 + qkv 100.7 + attn 33.5).

typedef __bf16 bf16;
typedef __bf16 bf16x4_t __attribute__((ext_vector_type(4)));
typedef __bf16 bf16x8_t __attribute__((ext_vector_type(8)));
typedef float f32x4_t __attribute__((ext_vector_type(4)));

static __device__ __forceinline__ void gload_lds16(const void* g, void* l) {
  // async global->LDS, 16B per lane; LDS dest is wave-uniform base + lane*16
  __builtin_amdgcn_global_load_lds((__attribute__((address_space(1))) void*)g,
                                   (__attribute__((address_space(3))) void*)l,
                                   16, 0, 0);
}

// ---------------- f32 -> bf16 conversion (memory-bound, float4 in / 8B out) ----
__global__ void cvt_f32_bf16(const float* __restrict__ in, bf16* __restrict__ out, int n4) {
  int i = blockIdx.x * blockDim.x + threadIdx.x;
  if (i >= n4) return;
  float4 v = reinterpret_cast<const float4*>(in)[i];
  bf16x4_t o;
  o[0] = (bf16)v.x; o[1] = (bf16)v.y; o[2] = (bf16)v.z; o[3] = (bf16)v.w;
  reinterpret_cast<bf16x4_t*>(out)[i] = o;
}

// ---------------- bf16 GEMM, C = A @ B^T (both K-major), m97 structure ---------
// A: [M][K], Bm: [N][K], Cout: [M][N]. OUT_BF16=1 -> bf16 store; 0 -> f32 + bias.
template<int OUT_BF16>
__global__ __launch_bounds__(256, 2)
void gemm_bt(const bf16* __restrict__ A, const bf16* __restrict__ Bm,
             void* __restrict__ Cout, const float* __restrict__ bias,
             int M, int N, int K) {
  constexpr int BM = 128, BN = 128, BK = 32;
  __shared__ __align__(16) bf16 sA[BM * BK];
  __shared__ __align__(16) bf16 sB[BN * BK];

  const int tid  = threadIdx.x;
  const int wave = tid >> 6;
  const int lane = tid & 63;
  const int row0 = blockIdx.y * BM;
  const int col0 = blockIdx.x * BN;
  const int wr = (wave >> 1) * 64;   // wave's 64x64 sub-tile
  const int wc = (wave & 1) * 64;
  const int fr = lane & 15;          // M-row (A) / N-col (B) within fragment
  const int g  = lane >> 4;          // lane group -> K sub-chunk
  const int srow = lane >> 2;        // staging: row within 16-row chunk
  const int scol = (lane & 3) * 8;   // staging: 8 bf16 (16B) per lane

  f32x4_t acc[4][4] = {};

  const bf16* aBase = A  + (size_t)(row0 + srow) * K + scol;
  const bf16* bBase = Bm + (size_t)(col0 + srow) * K + scol;

  const int nK = K / BK;
  for (int kt = 0; kt < nK; ++kt) {
    const int kb = kt * BK;
#pragma unroll
    for (int it = 0; it < 2; ++it) {
      const int chunk = it * 4 + wave;              // 8 chunks of 1KB per operand
      gload_lds16(aBase + (size_t)(chunk * 16) * K + kb, sA + chunk * 512);
      gload_lds16(bBase + (size_t)(chunk * 16) * K + kb, sB + chunk * 512);
    }
    __syncthreads();   // drains vmcnt per compiler barrier semantics

    bf16x8_t af[4], bfr[4];
#pragma unroll
    for (int m = 0; m < 4; ++m)
      af[m] = *reinterpret_cast<const bf16x8_t*>(sA + (wr + m * 16 + fr) * BK + g * 8);
#pragma unroll
    for (int n = 0; n < 4; ++n)
      bfr[n] = *reinterpret_cast<const bf16x8_t*>(sB + (wc + n * 16 + fr) * BK + g * 8);
#pragma unroll
    for (int m = 0; m < 4; ++m)
#pragma unroll
      for (int n = 0; n < 4; ++n)
        acc[m][n] = __builtin_amdgcn_mfma_f32_16x16x32_bf16(af[m], bfr[n], acc[m][n], 0, 0, 0);
    __syncthreads();
  }

  // epilogue: D row = g*4 + r, col = fr (verified m89 C/D layout)
#pragma unroll
  for (int m = 0; m < 4; ++m) {
    const int rbase = row0 + wr + m * 16 + g * 4;
#pragma unroll
    for (int n = 0; n < 4; ++n) {
      const int ccol = col0 + wc + n * 16 + fr;
#pragma unroll
      for (int r = 0; r < 4; ++r) {
        const size_t idx = (size_t)(rbase + r) * N + ccol;
        if constexpr (OUT_BF16) {
          reinterpret_cast<bf16*>(Cout)[idx] = (bf16)acc[m][n][r];
        } else {
          reinterpret_cast<float*>(Cout)[idx] = acc[m][n][r] + bias[ccol];
        }
      }
    }
  }
}

// ---------------- local 3x3 window attention -----------------------------------
// qkv: [B*N][3072] bf16 (q | k | v, each head h at cols h*64..h*64+63)
// out: [B*N][1024] bf16. One wave per (b,h,i); lane = d.
__global__ __launch_bounds__(256)
void local_attn(const bf16* __restrict__ qkv, bf16* __restrict__ outp) {
  const int lane = threadIdx.x & 63;
  const int wid  = blockIdx.x * 4 + (threadIdx.x >> 6); // i fastest -> k/v L2 reuse
  const int i  = wid & 1023;
  const int bh = wid >> 10;
  const int h  = bh & 15;
  const int b  = bh >> 4;
  const int r = i >> 5, c = i & 31;

  const float qd = (float)qkv[((size_t)(b * 1024 + i)) * 3072 + h * 64 + lane];

  float s[9];
#pragma unroll
  for (int dr = -1; dr <= 1; ++dr) {
#pragma unroll
    for (int dc = -1; dc <= 1; ++dc) {
      const int idx = (dr + 1) * 3 + (dc + 1);
      const int rr = r + dr, cc = c + dc;
      float sv = -1e30f;
      if (rr >= 0 && rr < 32 && cc >= 0 && cc < 32) {
        const int j = rr * 32 + cc;
        float p = qd * (float)qkv[((size_t)(b * 1024 + j)) * 3072 + 1024 + h * 64 + lane];
#pragma unroll
        for (int off = 32; off > 0; off >>= 1) p += __shfl_xor(p, off);
        sv = p * 0.125f;  // D^-0.5, all lanes hold full dot after butterfly
      }
      s[idx] = sv;
    }
  }
  float mx = s[0];
#pragma unroll
  for (int t = 1; t < 9; ++t) mx = fmaxf(mx, s[t]);

  float denom = 0.f, o = 0.f;
#pragma unroll
  for (int dr = -1; dr <= 1; ++dr) {
#pragma unroll
    for (int dc = -1; dc <= 1; ++dc) {
      const int idx = (dr + 1) * 3 + (dc + 1);
      const int rr = r + dr, cc = c + dc;
      if (rr >= 0 && rr < 32 && cc >= 0 && cc < 32) {
        const float p = __expf(s[idx] - mx);
        denom += p;
        const int j = rr * 32 + cc;
        o += p * (float)qkv[((size_t)(b * 1024 + j)) * 3072 + 2048 + h * 64 + lane];
      }
    }
  }
  outp[((size_t)(b * 1024 + i)) * 1024 + h * 64 + lane] = (bf16)(o / denom);
}

extern "C" void kernel_launch(void* const* d_in, const int* in_sizes, int n_in,
                              void* d_out, int out_size, void* d_ws, size_t ws_size,
                              hipStream_t stream) {
  const float* x      = (const float*)d_in[0];  // (16,1024,1024)
  const float* w_qkv  = (const float*)d_in[1];  // (3072,1024)
  const float* w_proj = (const float*)d_in[2];  // (1024,1024)
  const float* b_proj = (const float*)d_in[3];  // (1024,)
  float* out = (float*)d_out;

  const size_t nx   = (size_t)16384 * 1024;
  const size_t nwq  = (size_t)3072 * 1024;
  const size_t nwp  = (size_t)1024 * 1024;
  const size_t nqkv = (size_t)16384 * 3072;

  bf16* x_bf  = (bf16*)d_ws;
  bf16* wq_bf = x_bf + nx;
  bf16* wp_bf = wq_bf + nwq;
  bf16* qkv   = wp_bf + nwp;
  bf16* attn  = qkv + nqkv;

  cvt_f32_bf16<<<(int)(nx  / 4 / 256), 256, 0, stream>>>(x,      x_bf,  (int)(nx  / 4));
  cvt_f32_bf16<<<(int)(nwq / 4 / 256), 256, 0, stream>>>(w_qkv,  wq_bf, (int)(nwq / 4));
  cvt_f32_bf16<<<(int)(nwp / 4 / 256), 256, 0, stream>>>(w_proj, wp_bf, (int)(nwp / 4));

  // qkv = x @ w_qkv^T : M=16384, N=3072, K=1024
  gemm_bt<1><<<dim3(3072 / 128, 16384 / 128), 256, 0, stream>>>(
      x_bf, wq_bf, qkv, nullptr, 16384, 3072, 1024);

  // local window attention -> attn (bf16)
  local_attn<<<(16 * 16 * 1024) / 4, 256, 0, stream>>>(qkv, attn);

  // out = attn @ w_proj^T + b : M=16384, N=1024, K=1024
  gemm_bt<0><<<dim3(1024 / 128, 16384 / 128), 256, 0, stream>>>(
      attn, wp_bf, out, b_proj, 16384, 1024, 1024);
}

// Round 2
// 258.957 us; speedup vs baseline: 1.7111x; 1.7111x over previous
//
#include <hip/hip_runtime.h>
#include <hip/hip_bf16.h>
#include <stdint.h>

// LocalAttention: B=16, N=1024 (32x32 grid), C=1024, H=16, D=64.
// Pipeline: cvt(x,w_qkv,w_proj)->bf16 ; GEMM1 qkv = x@w_qkv^T (bf16 MFMA) ;
// local 3x3 window attention (8 tokens/wave x 8 lanes/token) ;
// GEMM2 out = attn@w_proj^T + b.
// Workspace: ~176.2 MB (x_bf 33.5 + wq 6.3 + wp 2.1 + qkv 100.7 + attn 33.5).

typedef __bf16 bf16;
typedef __bf16 bf16x4_t __attribute__((ext_vector_type(4)));
typedef __bf16 bf16x8_t __attribute__((ext_vector_type(8)));
typedef float f32x4_t __attribute__((ext_vector_type(4)));

static __device__ __forceinline__ void gload_lds16(const void* g, void* l) {
  __builtin_amdgcn_global_load_lds((__attribute__((address_space(1))) void*)g,
                                   (__attribute__((address_space(3))) void*)l,
                                   16, 0, 0);
}

// ---------------- f32 -> bf16 conversion ---------------------------------------
__global__ void cvt_f32_bf16(const float* __restrict__ in, bf16* __restrict__ out, int n4) {
  int i = blockIdx.x * blockDim.x + threadIdx.x;
  if (i >= n4) return;
  float4 v = reinterpret_cast<const float4*>(in)[i];
  bf16x4_t o;
  o[0] = (bf16)v.x; o[1] = (bf16)v.y; o[2] = (bf16)v.z; o[3] = (bf16)v.w;
  reinterpret_cast<bf16x4_t*>(out)[i] = o;
}

// ---------------- bf16 GEMM, C = A @ B^T (both K-major), m97 structure ---------
template<int OUT_BF16>
__global__ __launch_bounds__(256, 2)
void gemm_bt(const bf16* __restrict__ A, const bf16* __restrict__ Bm,
             void* __restrict__ Cout, const float* __restrict__ bias,
             int M, int N, int K) {
  constexpr int BM = 128, BN = 128, BK = 32;
  __shared__ __align__(16) bf16 sA[BM * BK];
  __shared__ __align__(16) bf16 sB[BN * BK];

  const int tid  = threadIdx.x;
  const int wave = tid >> 6;
  const int lane = tid & 63;
  const int row0 = blockIdx.y * BM;
  const int col0 = blockIdx.x * BN;
  const int wr = (wave >> 1) * 64;
  const int wc = (wave & 1) * 64;
  const int fr = lane & 15;
  const int g  = lane >> 4;
  const int srow = lane >> 2;
  const int scol = (lane & 3) * 8;

  f32x4_t acc[4][4] = {};

  const bf16* aBase = A  + (size_t)(row0 + srow) * K + scol;
  const bf16* bBase = Bm + (size_t)(col0 + srow) * K + scol;

  const int nK = K / BK;
  for (int kt = 0; kt < nK; ++kt) {
    const int kb = kt * BK;
#pragma unroll
    for (int it = 0; it < 2; ++it) {
      const int chunk = it * 4 + wave;
      gload_lds16(aBase + (size_t)(chunk * 16) * K + kb, sA + chunk * 512);
      gload_lds16(bBase + (size_t)(chunk * 16) * K + kb, sB + chunk * 512);
    }
    __syncthreads();

    bf16x8_t af[4], bfr[4];
#pragma unroll
    for (int m = 0; m < 4; ++m)
      af[m] = *reinterpret_cast<const bf16x8_t*>(sA + (wr + m * 16 + fr) * BK + g * 8);
#pragma unroll
    for (int n = 0; n < 4; ++n)
      bfr[n] = *reinterpret_cast<const bf16x8_t*>(sB + (wc + n * 16 + fr) * BK + g * 8);
#pragma unroll
    for (int m = 0; m < 4; ++m)
#pragma unroll
      for (int n = 0; n < 4; ++n)
        acc[m][n] = __builtin_amdgcn_mfma_f32_16x16x32_bf16(af[m], bfr[n], acc[m][n], 0, 0, 0);
    __syncthreads();
  }

#pragma unroll
  for (int m = 0; m < 4; ++m) {
    const int rbase = row0 + wr + m * 16 + g * 4;
#pragma unroll
    for (int n = 0; n < 4; ++n) {
      const int ccol = col0 + wc + n * 16 + fr;
#pragma unroll
      for (int r = 0; r < 4; ++r) {
        const size_t idx = (size_t)(rbase + r) * N + ccol;
        if constexpr (OUT_BF16) {
          reinterpret_cast<bf16*>(Cout)[idx] = (bf16)acc[m][n][r];
        } else {
          reinterpret_cast<float*>(Cout)[idx] = acc[m][n][r] + bias[ccol];
        }
      }
    }
  }
}

// ---------------- local 3x3 window attention -----------------------------------
// qkv: [B*N][3072] bf16 (q|k|v, head h at h*64). out: [B*N][1024] bf16.
// 8 tokens per wave; 8 lanes per token, each lane owns an 8-elem d-chunk (16B).
// Dot = 8 serial FMAs + 3-step intra-group butterfly (9 independent chains).
__global__ __launch_bounds__(256)
void local_attn(const bf16* __restrict__ qkv, bf16* __restrict__ outp) {
  const int tid  = threadIdx.x;
  const int wave = tid >> 6, lane = tid & 63;
  const int tsub = lane >> 3, ch = lane & 7;
  const int gt = (blockIdx.x * 4 + wave) * 8 + tsub;   // global token id
  const int i  = gt & 1023;
  const int bh = gt >> 10;
  const int h  = bh & 15, b = bh >> 4;
  const int r  = i >> 5, c = i & 31;

  const bf16* base = qkv + (size_t)(b * 1024) * 3072 + h * 64 + ch * 8;

  // q chunk -> f32 registers (reused by all 9 dots)
  bf16x8_t qv = *reinterpret_cast<const bf16x8_t*>(base + (size_t)i * 3072);
  float qf[8];
#pragma unroll
  for (int e = 0; e < 8; ++e) qf[e] = (float)qv[e];

  float s[9];
  bool valid[9];
#pragma unroll
  for (int dr = -1; dr <= 1; ++dr) {
#pragma unroll
    for (int dc = -1; dc <= 1; ++dc) {
      const int idx = (dr + 1) * 3 + (dc + 1);
      const int rr = r + dr, cc = c + dc;
      valid[idx] = (rr >= 0 && rr < 32 && cc >= 0 && cc < 32);
      float sv = -1e30f;
      if (valid[idx]) {
        const int j = rr * 32 + cc;
        bf16x8_t kv = *reinterpret_cast<const bf16x8_t*>(base + (size_t)j * 3072 + 1024);
        float ps = 0.f;
#pragma unroll
        for (int e = 0; e < 8; ++e) ps += qf[e] * (float)kv[e];
        ps += __shfl_xor(ps, 1);
        ps += __shfl_xor(ps, 2);
        ps += __shfl_xor(ps, 4);   // all 8 lanes of the token hold full dot
        sv = ps * 0.125f;          // D^-0.5
      }
      s[idx] = sv;
    }
  }

  float mx = s[0];
#pragma unroll
  for (int t = 1; t < 9; ++t) mx = fmaxf(mx, s[t]);

  float p[9], denom = 0.f;
#pragma unroll
  for (int t = 0; t < 9; ++t) {
    p[t] = valid[t] ? __expf(s[t] - mx) : 0.f;
    denom += p[t];
  }

  float o[8] = {};
#pragma unroll
  for (int dr = -1; dr <= 1; ++dr) {
#pragma unroll
    for (int dc = -1; dc <= 1; ++dc) {
      const int idx = (dr + 1) * 3 + (dc + 1);
      if (valid[idx]) {
        const int j = (r + dr) * 32 + (c + dc);
        bf16x8_t vv = *reinterpret_cast<const bf16x8_t*>(base + (size_t)j * 3072 + 2048);
        const float pw = p[idx];
#pragma unroll
        for (int e = 0; e < 8; ++e) o[e] += pw * (float)vv[e];
      }
    }
  }

  const float inv = 1.f / denom;
  bf16x8_t ov;
#pragma unroll
  for (int e = 0; e < 8; ++e) ov[e] = (bf16)(o[e] * inv);
  *reinterpret_cast<bf16x8_t*>(outp + (size_t)(b * 1024 + i) * 1024 + h * 64 + ch * 8) = ov;
}

extern "C" void kernel_launch(void* const* d_in, const int* in_sizes, int n_in,
                              void* d_out, int out_size, void* d_ws, size_t ws_size,
                              hipStream_t stream) {
  const float* x      = (const float*)d_in[0];
  const float* w_qkv  = (const float*)d_in[1];
  const float* w_proj = (const float*)d_in[2];
  const float* b_proj = (const float*)d_in[3];
  float* out = (float*)d_out;

  const size_t nx   = (size_t)16384 * 1024;
  const size_t nwq  = (size_t)3072 * 1024;
  const size_t nwp  = (size_t)1024 * 1024;
  const size_t nqkv = (size_t)16384 * 3072;

  bf16* x_bf  = (bf16*)d_ws;
  bf16* wq_bf = x_bf + nx;
  bf16* wp_bf = wq_bf + nwq;
  bf16* qkv   = wp_bf + nwp;
  bf16* attn  = qkv + nqkv;

  cvt_f32_bf16<<<(int)(nx  / 4 / 256), 256, 0, stream>>>(x,      x_bf,  (int)(nx  / 4));
  cvt_f32_bf16<<<(int)(nwq / 4 / 256), 256, 0, stream>>>(w_qkv,  wq_bf, (int)(nwq / 4));
  cvt_f32_bf16<<<(int)(nwp / 4 / 256), 256, 0, stream>>>(w_proj, wp_bf, (int)(nwp / 4));

  // qkv = x @ w_qkv^T : M=16384, N=3072, K=1024
  gemm_bt<1><<<dim3(3072 / 128, 16384 / 128), 256, 0, stream>>>(
      x_bf, wq_bf, qkv, nullptr, 16384, 3072, 1024);

  // local window attention: 262144 tokens, 32 tokens/block
  local_attn<<<8192, 256, 0, stream>>>(qkv, attn);

  // out = attn @ w_proj^T + b : M=16384, N=1024, K=1024
  gemm_bt<0><<<dim3(1024 / 128, 16384 / 128), 256, 0, stream>>>(
      attn, wp_bf, out, b_proj, 16384, 1024, 1024);
}

// Round 3
// 249.800 us; speedup vs baseline: 1.7738x; 1.0367x over previous
//
#include <hip/hip_runtime.h>
#include <hip/hip_bf16.h>
#include <stdint.h>

// LocalAttention: B=16, N=1024 (32x32 grid), C=1024, H=16, D=64.
// cvt->bf16 ; GEMM1 qkv=x@w_qkv^T (256^2 8-wave deep-pipelined bf16 MFMA) ;
// local 3x3 window attention ; GEMM2 out=attn@w_proj^T+b (same GEMM).
// Workspace: ~176.2 MB.

typedef __bf16 bf16;
typedef __bf16 bf16x4_t __attribute__((ext_vector_type(4)));
typedef __bf16 bf16x8_t __attribute__((ext_vector_type(8)));
typedef float f32x4_t __attribute__((ext_vector_type(4)));

static __device__ __forceinline__ void gload_lds16(const void* g, void* l) {
  __builtin_amdgcn_global_load_lds((__attribute__((address_space(1))) void*)g,
                                   (__attribute__((address_space(3))) void*)l,
                                   16, 0, 0);
}

// raw s_barrier with compile-time memory fences (no vmcnt/lgkm drain)
static __device__ __forceinline__ void block_barrier() {
  asm volatile("" ::: "memory");
  __builtin_amdgcn_s_barrier();
  asm volatile("" ::: "memory");
}

// ---------------- f32 -> bf16 conversion ---------------------------------------
__global__ void cvt_f32_bf16(const float* __restrict__ in, bf16* __restrict__ out, int n4) {
  int i = blockIdx.x * blockDim.x + threadIdx.x;
  if (i >= n4) return;
  float4 v = reinterpret_cast<const float4*>(in)[i];
  bf16x4_t o;
  o[0] = (bf16)v.x; o[1] = (bf16)v.y; o[2] = (bf16)v.z; o[3] = (bf16)v.w;
  reinterpret_cast<bf16x4_t*>(out)[i] = o;
}

// ---------------- 256x256 8-wave deep-pipelined bf16 GEMM, C = A @ B^T ---------
// A: [M][K], Bm: [N][K] (both K-major). 512 threads = 8 waves (2M x 4N).
// LDS 128 KiB: 2 slots x (A 256x64 + B 256x64) bf16, T2-swizzled
// (linear global_load_lds dest + inverse-swizzled global src + swizzled ds_read).
// Schedule: per K-tile 4 phases {12 ds_read_b128; barrier; lgkmcnt(0); 16 MFMA;
// barrier}; stage tile t+2 at tile end; counted vmcnt(8) (never drain in loop).
template<int OUT_BF16>
__global__ __launch_bounds__(512, 2)
void gemm256(const bf16* __restrict__ A, const bf16* __restrict__ Bm,
             void* __restrict__ Cout, const float* __restrict__ bias,
             int M, int N, int K) {
  extern __shared__ __align__(16) bf16 lds[];

  const int tid = threadIdx.x;
  const int w = tid >> 6, lane = tid & 63;
  const int fr = lane & 15, g = lane >> 4;
  const int wr = w >> 2, wc = w & 3;          // wave grid 2 x 4

  // T1: XCD-aware bijective swizzle (nwg % 8 == 0 for both call sites)
  const int nwg = gridDim.x * gridDim.y;
  int lid = blockIdx.y * gridDim.x + blockIdx.x;
  lid = (lid & 7) * (nwg >> 3) + (lid >> 3);
  const int bx = lid % gridDim.x, by = lid / gridDim.x;
  const int row0 = by * 256, col0 = bx * 256;

  const bf16* Ag = A + (size_t)row0 * K;
  const bf16* Bg = Bm + (size_t)col0 * K;
  const int rsub = tid >> 3;                               // 0..63: row within half
  const int csw  = ((tid & 7) * 8) ^ ((rsub & 7) << 3);    // inverse-swizzled src col (elems)
  const int nkt  = K >> 6;

  f32x4_t acc[8][4] = {};

  auto stage = [&](int kt, int slot) {
    const int kb = kt << 6;
    bf16* sl = lds + slot * 32768;
#pragma unroll
    for (int n = 0; n < 4; ++n) {
      gload_lds16(Ag + (size_t)(rsub + n * 64) * K + kb + csw,
                  sl + n * 4096 + w * 512);                       // A: 16 KB x 2 halves
      gload_lds16(Bg + (size_t)(rsub + n * 64) * K + kb + csw,
                  sl + 16384 + n * 4096 + w * 512);               // B
    }
  };

  // prologue: tiles 0,1 in flight; wait tile 0 (8 newest = tile 1 stay in flight)
  stage(0, 0);
  stage(1, 1);
  asm volatile("s_waitcnt vmcnt(8)" ::: "memory");
  block_barrier();

  for (int kt = 0; kt < nkt; ++kt) {
    const bf16* sA = lds + (kt & 1) * 32768;
    const bf16* sB = sA + 16384;
#pragma unroll
    for (int ph = 0; ph < 4; ++ph) {
      const int mq = ph >> 1, nq = ph & 1;    // C-quadrant of wave's 128x64
      bf16x8_t af[4][2], bfr[2][2];
#pragma unroll
      for (int i = 0; i < 4; ++i) {
        const int row = wr * 128 + (mq * 4 + i) * 16 + fr;
#pragma unroll
        for (int kh = 0; kh < 2; ++kh) {
          int bo = (row << 7) + (kh << 6) + (g << 4);
          bo ^= (row & 7) << 4;               // T2 swizzle (row&7 == fr&7)
          af[i][kh] = *reinterpret_cast<const bf16x8_t*>(
              reinterpret_cast<const char*>(sA) + bo);
        }
      }
#pragma unroll
      for (int j = 0; j < 2; ++j) {
        const int row = wc * 64 + (nq * 2 + j) * 16 + fr;
#pragma unroll
        for (int kh = 0; kh < 2; ++kh) {
          int bo = (row << 7) + (kh << 6) + (g << 4);
          bo ^= (row & 7) << 4;
          bfr[j][kh] = *reinterpret_cast<const bf16x8_t*>(
              reinterpret_cast<const char*>(sB) + bo);
        }
      }
      block_barrier();
      asm volatile("s_waitcnt lgkmcnt(0)" ::: "memory");
      __builtin_amdgcn_sched_barrier(0);
      __builtin_amdgcn_s_setprio(1);
#pragma unroll
      for (int i = 0; i < 4; ++i)
#pragma unroll
        for (int j = 0; j < 2; ++j)
#pragma unroll
          for (int kh = 0; kh < 2; ++kh)
            acc[mq * 4 + i][nq * 2 + j] = __builtin_amdgcn_mfma_f32_16x16x32_bf16(
                af[i][kh], bfr[j][kh], acc[mq * 4 + i][nq * 2 + j], 0, 0, 0);
      __builtin_amdgcn_s_setprio(0);
      block_barrier();
    }
    // all waves have drained their reads of slot kt&1 (lgkmcnt(0) preceded the
    // last barrier) -> safe to overwrite it with tile kt+2
    if (kt + 2 < nkt) stage(kt + 2, kt & 1);
    if (kt < nkt - 2) {
      asm volatile("s_waitcnt vmcnt(8)" ::: "memory");   // tile kt+1 landed
    } else {
      asm volatile("s_waitcnt vmcnt(0)" ::: "memory");   // tail drain
    }
    block_barrier();
  }

  // epilogue: D row = g*4+r (M), col = fr (N) per verified m89 layout
#pragma unroll
  for (int fm = 0; fm < 8; ++fm) {
    const int rbase = row0 + wr * 128 + fm * 16 + g * 4;
#pragma unroll
    for (int fn = 0; fn < 4; ++fn) {
      const int col = col0 + wc * 64 + fn * 16 + fr;
#pragma unroll
      for (int r = 0; r < 4; ++r) {
        const size_t idx = (size_t)(rbase + r) * N + col;
        if constexpr (OUT_BF16) {
          reinterpret_cast<bf16*>(Cout)[idx] = (bf16)acc[fm][fn][r];
        } else {
          reinterpret_cast<float*>(Cout)[idx] = acc[fm][fn][r] + bias[col];
        }
      }
    }
  }
}

// ---------------- local 3x3 window attention -----------------------------------
// qkv: [B*N][3072] bf16 (q|k|v, head h at h*64). out: [B*N][1024] bf16.
// 8 tokens per wave; 8 lanes per token, each lane owns an 8-elem d-chunk (16B).
__global__ __launch_bounds__(256)
void local_attn(const bf16* __restrict__ qkv, bf16* __restrict__ outp) {
  const int tid  = threadIdx.x;
  const int wave = tid >> 6, lane = tid & 63;
  const int tsub = lane >> 3, ch = lane & 7;
  const int gt = (blockIdx.x * 4 + wave) * 8 + tsub;
  const int i  = gt & 1023;
  const int bh = gt >> 10;
  const int h  = bh & 15, b = bh >> 4;
  const int r  = i >> 5, c = i & 31;

  const bf16* base = qkv + (size_t)(b * 1024) * 3072 + h * 64 + ch * 8;

  bf16x8_t qv = *reinterpret_cast<const bf16x8_t*>(base + (size_t)i * 3072);
  float qf[8];
#pragma unroll
  for (int e = 0; e < 8; ++e) qf[e] = (float)qv[e];

  float s[9];
  bool valid[9];
#pragma unroll
  for (int dr = -1; dr <= 1; ++dr) {
#pragma unroll
    for (int dc = -1; dc <= 1; ++dc) {
      const int idx = (dr + 1) * 3 + (dc + 1);
      const int rr = r + dr, cc = c + dc;
      valid[idx] = (rr >= 0 && rr < 32 && cc >= 0 && cc < 32);
      float sv = -1e30f;
      if (valid[idx]) {
        const int j = rr * 32 + cc;
        bf16x8_t kv = *reinterpret_cast<const bf16x8_t*>(base + (size_t)j * 3072 + 1024);
        float ps = 0.f;
#pragma unroll
        for (int e = 0; e < 8; ++e) ps += qf[e] * (float)kv[e];
        ps += __shfl_xor(ps, 1);
        ps += __shfl_xor(ps, 2);
        ps += __shfl_xor(ps, 4);
        sv = ps * 0.125f;
      }
      s[idx] = sv;
    }
  }

  float mx = s[0];
#pragma unroll
  for (int t = 1; t < 9; ++t) mx = fmaxf(mx, s[t]);

  float p[9], denom = 0.f;
#pragma unroll
  for (int t = 0; t < 9; ++t) {
    p[t] = valid[t] ? __expf(s[t] - mx) : 0.f;
    denom += p[t];
  }

  float o[8] = {};
#pragma unroll
  for (int dr = -1; dr <= 1; ++dr) {
#pragma unroll
    for (int dc = -1; dc <= 1; ++dc) {
      const int idx = (dr + 1) * 3 + (dc + 1);
      if (valid[idx]) {
        const int j = (r + dr) * 32 + (c + dc);
        bf16x8_t vv = *reinterpret_cast<const bf16x8_t*>(base + (size_t)j * 3072 + 2048);
        const float pw = p[idx];
#pragma unroll
        for (int e = 0; e < 8; ++e) o[e] += pw * (float)vv[e];
      }
    }
  }

  const float inv = 1.f / denom;
  bf16x8_t ov;
#pragma unroll
  for (int e = 0; e < 8; ++e) ov[e] = (bf16)(o[e] * inv);
  *reinterpret_cast<bf16x8_t*>(outp + (size_t)(b * 1024 + i) * 1024 + h * 64 + ch * 8) = ov;
}

extern "C" void kernel_launch(void* const* d_in, const int* in_sizes, int n_in,
                              void* d_out, int out_size, void* d_ws, size_t ws_size,
                              hipStream_t stream) {
  const float* x      = (const float*)d_in[0];
  const float* w_qkv  = (const float*)d_in[1];
  const float* w_proj = (const float*)d_in[2];
  const float* b_proj = (const float*)d_in[3];
  float* out = (float*)d_out;

  const size_t nx   = (size_t)16384 * 1024;
  const size_t nwq  = (size_t)3072 * 1024;
  const size_t nwp  = (size_t)1024 * 1024;
  const size_t nqkv = (size_t)16384 * 3072;

  bf16* x_bf  = (bf16*)d_ws;
  bf16* wq_bf = x_bf + nx;
  bf16* wp_bf = wq_bf + nwq;
  bf16* qkv   = wp_bf + nwp;
  bf16* attn  = qkv + nqkv;

  (void)hipFuncSetAttribute((const void*)&gemm256<1>,
                            hipFuncAttributeMaxDynamicSharedMemorySize, 131072);
  (void)hipFuncSetAttribute((const void*)&gemm256<0>,
                            hipFuncAttributeMaxDynamicSharedMemorySize, 131072);

  cvt_f32_bf16<<<(int)(nx  / 4 / 256), 256, 0, stream>>>(x,      x_bf,  (int)(nx  / 4));
  cvt_f32_bf16<<<(int)(nwq / 4 / 256), 256, 0, stream>>>(w_qkv,  wq_bf, (int)(nwq / 4));
  cvt_f32_bf16<<<(int)(nwp / 4 / 256), 256, 0, stream>>>(w_proj, wp_bf, (int)(nwp / 4));

  // qkv = x @ w_qkv^T : M=16384, N=3072, K=1024 ; grid 12x64 = 768 (%8==0)
  gemm256<1><<<dim3(3072 / 256, 16384 / 256), 512, 131072, stream>>>(
      x_bf, wq_bf, qkv, nullptr, 16384, 3072, 1024);

  // local window attention: 262144 tokens, 32 tokens/block
  local_attn<<<8192, 256, 0, stream>>>(qkv, attn);

  // out = attn @ w_proj^T + b : M=16384, N=1024, K=1024 ; grid 4x64 = 256
  gemm256<0><<<dim3(1024 / 256, 16384 / 256), 512, 131072, stream>>>(
      attn, wp_bf, out, b_proj, 16384, 1024, 1024);
}

// Round 4
// 216.146 us; speedup vs baseline: 2.0500x; 1.1557x over previous
//
#include <hip/hip_runtime.h>
#include <hip/hip_bf16.h>
#include <stdint.h>

// LocalAttention: B=16, N=1024 (32x32 grid), C=1024, H=16, D=64.
// cvt->bf16 ; GEMM1 qkv=x@w_qkv^T (256^2 8-wave bf16 MFMA, compiler-scheduled
// tile body, counted-vmcnt dbuf staging, T2 LDS swizzle) ; local 3x3 window
// attention ; GEMM2 out=attn@w_proj^T+b. Workspace: ~176.2 MB.

typedef __bf16 bf16;
typedef __bf16 bf16x4_t __attribute__((ext_vector_type(4)));
typedef __bf16 bf16x8_t __attribute__((ext_vector_type(8)));
typedef float f32x4_t __attribute__((ext_vector_type(4)));

static __device__ __forceinline__ void gload_lds16(const void* g, void* l) {
  __builtin_amdgcn_global_load_lds((__attribute__((address_space(1))) void*)g,
                                   (__attribute__((address_space(3))) void*)l,
                                   16, 0, 0);
}

// raw s_barrier with compile-time memory fences (no vmcnt/lgkm drain)
static __device__ __forceinline__ void block_barrier() {
  asm volatile("" ::: "memory");
  __builtin_amdgcn_s_barrier();
  asm volatile("" ::: "memory");
}

// ---------------- f32 -> bf16 conversion ---------------------------------------
__global__ void cvt_f32_bf16(const float* __restrict__ in, bf16* __restrict__ out, int n4) {
  int i = blockIdx.x * blockDim.x + threadIdx.x;
  if (i >= n4) return;
  float4 v = reinterpret_cast<const float4*>(in)[i];
  bf16x4_t o;
  o[0] = (bf16)v.x; o[1] = (bf16)v.y; o[2] = (bf16)v.z; o[3] = (bf16)v.w;
  reinterpret_cast<bf16x4_t*>(out)[i] = o;
}

// ---------------- 256x256 8-wave bf16 GEMM, C = A @ B^T ------------------------
// A: [M][K], Bm: [N][K] (both K-major). 512 threads = 8 waves (2M x 4N).
// LDS 128 KiB: 2 slots x (A 256x64 + B 256x64) bf16, T2-swizzled
// (linear global_load_lds dest + inverse-swizzled global src + swizzled ds_read).
// Tile body is straight-line (24 ds_read_b128, each fragment read ONCE, zig-zag
// quadrant order) -- compiler inserts counted lgkmcnt and pipelines the reads.
// Only 2 barriers per K-tile (around the stage write). Staging: 2-tile-deep,
// clustered at tile end, counted vmcnt(8) (never drain in main loop).
template<int OUT_BF16>
__global__ __launch_bounds__(512, 2)
void gemm256(const bf16* __restrict__ A, const bf16* __restrict__ Bm,
             void* __restrict__ Cout, const float* __restrict__ bias,
             int M, int N, int K) {
  extern __shared__ __align__(16) bf16 lds[];

  const int tid = threadIdx.x;
  const int w = tid >> 6, lane = tid & 63;
  const int fr = lane & 15, g = lane >> 4;
  const int wr = w >> 2, wc = w & 3;          // wave grid 2 x 4

  // T1: XCD-aware bijective swizzle (nwg % 8 == 0 for both call sites)
  const int nwg = gridDim.x * gridDim.y;
  int lid = blockIdx.y * gridDim.x + blockIdx.x;
  lid = (lid & 7) * (nwg >> 3) + (lid >> 3);
  const int bx = lid % gridDim.x, by = lid / gridDim.x;
  const int row0 = by * 256, col0 = bx * 256;

  const bf16* Ag = A + (size_t)row0 * K;
  const bf16* Bg = Bm + (size_t)col0 * K;
  const int rsub = tid >> 3;                               // 0..63: row within 64-row chunk
  const int csw  = ((tid & 7) * 8) ^ ((rsub & 7) << 3);    // inverse-swizzled src col (elems)
  const int nkt  = K >> 6;

  f32x4_t acc[8][4] = {};

  auto stage = [&](int kt, int slot) {
    const int kb = kt << 6;
    bf16* sl = lds + slot * 32768;
#pragma unroll
    for (int n = 0; n < 4; ++n) {
      gload_lds16(Ag + (size_t)(rsub + n * 64) * K + kb + csw,
                  sl + n * 4096 + w * 512);                       // A 32KB
      gload_lds16(Bg + (size_t)(rsub + n * 64) * K + kb + csw,
                  sl + 16384 + n * 4096 + w * 512);               // B 32KB
    }
  };

  const int axor = (fr & 7) << 4;   // T2 read-side XOR (lane-constant)

  // prologue: tiles 0,1 in flight; wait tile 0 (8 newest = tile 1 stay in flight)
  stage(0, 0);
  stage(1, 1);
  asm volatile("s_waitcnt vmcnt(8)" ::: "memory");
  block_barrier();

  for (int kt = 0; kt < nkt; ++kt) {
    const char* cA = reinterpret_cast<const char*>(lds + (kt & 1) * 32768);
    const char* cB = cA + 32768;

    bf16x8_t a0[4][2], a1[4][2], b0[2][2], b1[2][2];

    auto lda = [&](bf16x8_t (&dst)[4][2], int q) {
#pragma unroll
      for (int i = 0; i < 4; ++i) {
        const int row = wr * 128 + (q * 4 + i) * 16 + fr;
#pragma unroll
        for (int kh = 0; kh < 2; ++kh) {
          const int bo = (row << 7) + (((kh << 6) + (g << 4)) ^ axor);
          dst[i][kh] = *reinterpret_cast<const bf16x8_t*>(cA + bo);
        }
      }
    };
    auto ldb = [&](bf16x8_t (&dst)[2][2], int q) {
#pragma unroll
      for (int j = 0; j < 2; ++j) {
        const int row = wc * 64 + (q * 2 + j) * 16 + fr;
#pragma unroll
        for (int kh = 0; kh < 2; ++kh) {
          const int bo = (row << 7) + (((kh << 6) + (g << 4)) ^ axor);
          dst[j][kh] = *reinterpret_cast<const bf16x8_t*>(cB + bo);
        }
      }
    };

    // zig-zag quadrant order: (0,0) -> (0,1) -> (1,1) -> (1,0); each frag read once
    lda(a0, 0);
    ldb(b0, 0);
#pragma unroll
    for (int i = 0; i < 4; ++i)
#pragma unroll
      for (int j = 0; j < 2; ++j)
#pragma unroll
        for (int kh = 0; kh < 2; ++kh)
          acc[i][j] = __builtin_amdgcn_mfma_f32_16x16x32_bf16(
              a0[i][kh], b0[j][kh], acc[i][j], 0, 0, 0);
    ldb(b1, 1);
#pragma unroll
    for (int i = 0; i < 4; ++i)
#pragma unroll
      for (int j = 0; j < 2; ++j)
#pragma unroll
        for (int kh = 0; kh < 2; ++kh)
          acc[i][2 + j] = __builtin_amdgcn_mfma_f32_16x16x32_bf16(
              a0[i][kh], b1[j][kh], acc[i][2 + j], 0, 0, 0);
    lda(a1, 1);
#pragma unroll
    for (int i = 0; i < 4; ++i)
#pragma unroll
      for (int j = 0; j < 2; ++j)
#pragma unroll
        for (int kh = 0; kh < 2; ++kh)
          acc[4 + i][2 + j] = __builtin_amdgcn_mfma_f32_16x16x32_bf16(
              a1[i][kh], b1[j][kh], acc[4 + i][2 + j], 0, 0, 0);
#pragma unroll
    for (int i = 0; i < 4; ++i)
#pragma unroll
      for (int j = 0; j < 2; ++j)
#pragma unroll
        for (int kh = 0; kh < 2; ++kh)
          acc[4 + i][j] = __builtin_amdgcn_mfma_f32_16x16x32_bf16(
              a1[i][kh], b0[j][kh], acc[4 + i][j], 0, 0, 0);

    // all waves' reads of slot kt&1 are complete before their barrier arrival
    // (every ds_read is consumed by an MFMA above) -> safe to overwrite below
    block_barrier();
    if (kt + 2 < nkt) stage(kt + 2, kt & 1);
    if (kt < nkt - 2) {
      asm volatile("s_waitcnt vmcnt(8)" ::: "memory");   // tile kt+1 landed
    } else {
      asm volatile("s_waitcnt vmcnt(0)" ::: "memory");   // tail drain
    }
    block_barrier();
  }

  // epilogue: D row = g*4+r (M), col = fr (N) per verified m89 layout
#pragma unroll
  for (int fm = 0; fm < 8; ++fm) {
    const int rbase = row0 + wr * 128 + fm * 16 + g * 4;
#pragma unroll
    for (int fn = 0; fn < 4; ++fn) {
      const int col = col0 + wc * 64 + fn * 16 + fr;
#pragma unroll
      for (int r = 0; r < 4; ++r) {
        const size_t idx = (size_t)(rbase + r) * N + col;
        if constexpr (OUT_BF16) {
          reinterpret_cast<bf16*>(Cout)[idx] = (bf16)acc[fm][fn][r];
        } else {
          reinterpret_cast<float*>(Cout)[idx] = acc[fm][fn][r] + bias[col];
        }
      }
    }
  }
}

// ---------------- local 3x3 window attention -----------------------------------
// qkv: [B*N][3072] bf16 (q|k|v, head h at h*64). out: [B*N][1024] bf16.
// 8 tokens per wave; 8 lanes per token, each lane owns an 8-elem d-chunk (16B).
__global__ __launch_bounds__(256)
void local_attn(const bf16* __restrict__ qkv, bf16* __restrict__ outp) {
  const int tid  = threadIdx.x;
  const int wave = tid >> 6, lane = tid & 63;
  const int tsub = lane >> 3, ch = lane & 7;
  const int gt = (blockIdx.x * 4 + wave) * 8 + tsub;
  const int i  = gt & 1023;
  const int bh = gt >> 10;
  const int h  = bh & 15, b = bh >> 4;
  const int r  = i >> 5, c = i & 31;

  const bf16* base = qkv + (size_t)(b * 1024) * 3072 + h * 64 + ch * 8;

  bf16x8_t qv = *reinterpret_cast<const bf16x8_t*>(base + (size_t)i * 3072);
  float qf[8];
#pragma unroll
  for (int e = 0; e < 8; ++e) qf[e] = (float)qv[e];

  float s[9];
  bool valid[9];
#pragma unroll
  for (int dr = -1; dr <= 1; ++dr) {
#pragma unroll
    for (int dc = -1; dc <= 1; ++dc) {
      const int idx = (dr + 1) * 3 + (dc + 1);
      const int rr = r + dr, cc = c + dc;
      valid[idx] = (rr >= 0 && rr < 32 && cc >= 0 && cc < 32);
      float sv = -1e30f;
      if (valid[idx]) {
        const int j = rr * 32 + cc;
        bf16x8_t kv = *reinterpret_cast<const bf16x8_t*>(base + (size_t)j * 3072 + 1024);
        float ps = 0.f;
#pragma unroll
        for (int e = 0; e < 8; ++e) ps += qf[e] * (float)kv[e];
        ps += __shfl_xor(ps, 1);
        ps += __shfl_xor(ps, 2);
        ps += __shfl_xor(ps, 4);
        sv = ps * 0.125f;
      }
      s[idx] = sv;
    }
  }

  float mx = s[0];
#pragma unroll
  for (int t = 1; t < 9; ++t) mx = fmaxf(mx, s[t]);

  float p[9], denom = 0.f;
#pragma unroll
  for (int t = 0; t < 9; ++t) {
    p[t] = valid[t] ? __expf(s[t] - mx) : 0.f;
    denom += p[t];
  }

  float o[8] = {};
#pragma unroll
  for (int dr = -1; dr <= 1; ++dr) {
#pragma unroll
    for (int dc = -1; dc <= 1; ++dc) {
      const int idx = (dr + 1) * 3 + (dc + 1);
      if (valid[idx]) {
        const int j = (r + dr) * 32 + (c + dc);
        bf16x8_t vv = *reinterpret_cast<const bf16x8_t*>(base + (size_t)j * 3072 + 2048);
        const float pw = p[idx];
#pragma unroll
        for (int e = 0; e < 8; ++e) o[e] += pw * (float)vv[e];
      }
    }
  }

  const float inv = 1.f / denom;
  bf16x8_t ov;
#pragma unroll
  for (int e = 0; e < 8; ++e) ov[e] = (bf16)(o[e] * inv);
  *reinterpret_cast<bf16x8_t*>(outp + (size_t)(b * 1024 + i) * 1024 + h * 64 + ch * 8) = ov;
}

extern "C" void kernel_launch(void* const* d_in, const int* in_sizes, int n_in,
                              void* d_out, int out_size, void* d_ws, size_t ws_size,
                              hipStream_t stream) {
  const float* x      = (const float*)d_in[0];
  const float* w_qkv  = (const float*)d_in[1];
  const float* w_proj = (const float*)d_in[2];
  const float* b_proj = (const float*)d_in[3];
  float* out = (float*)d_out;

  const size_t nx   = (size_t)16384 * 1024;
  const size_t nwq  = (size_t)3072 * 1024;
  const size_t nwp  = (size_t)1024 * 1024;
  const size_t nqkv = (size_t)16384 * 3072;

  bf16* x_bf  = (bf16*)d_ws;
  bf16* wq_bf = x_bf + nx;
  bf16* wp_bf = wq_bf + nwq;
  bf16* qkv   = wp_bf + nwp;
  bf16* attn  = qkv + nqkv;

  (void)hipFuncSetAttribute((const void*)&gemm256<1>,
                            hipFuncAttributeMaxDynamicSharedMemorySize, 131072);
  (void)hipFuncSetAttribute((const void*)&gemm256<0>,
                            hipFuncAttributeMaxDynamicSharedMemorySize, 131072);

  cvt_f32_bf16<<<(int)(nx  / 4 / 256), 256, 0, stream>>>(x,      x_bf,  (int)(nx  / 4));
  cvt_f32_bf16<<<(int)(nwq / 4 / 256), 256, 0, stream>>>(w_qkv,  wq_bf, (int)(nwq / 4));
  cvt_f32_bf16<<<(int)(nwp / 4 / 256), 256, 0, stream>>>(w_proj, wp_bf, (int)(nwp / 4));

  // qkv = x @ w_qkv^T : M=16384, N=3072, K=1024 ; grid 12x64 = 768 (%8==0)
  gemm256<1><<<dim3(3072 / 256, 16384 / 256), 512, 131072, stream>>>(
      x_bf, wq_bf, qkv, nullptr, 16384, 3072, 1024);

  // local window attention: 262144 tokens, 32 tokens/block
  local_attn<<<8192, 256, 0, stream>>>(qkv, attn);

  // out = attn @ w_proj^T + b : M=16384, N=1024, K=1024 ; grid 4x64 = 256
  gemm256<0><<<dim3(1024 / 256, 16384 / 256), 512, 131072, stream>>>(
      attn, wp_bf, out, b_proj, 16384, 1024, 1024);
}